// Round 2
// baseline (8960.004 us; speedup 1.0000x reference)
//
#include <hip/hip_runtime.h>
#include <stdint.h>

typedef __bf16 bf16;
typedef __attribute__((ext_vector_type(8))) __bf16 bf16x8;
typedef __attribute__((ext_vector_type(4))) float floatx4;

#define NTOK   1024     // tokens per batch (N)
#define TOKS   8192     // B*N
#define HID_   1024
#define FFN_   2730
#define FFNP   2752     // FFN padded to mult of 32
#define X12N   5460     // 2*FFN

#define EPI_BF16  0
#define EPI_QKV   1
#define EPI_RESID 2

// ---------------------------------------------------------------- fp32 -> bf16 weight conversion
__global__ __launch_bounds__(256) void conv_bf16(const float* __restrict__ in, bf16* __restrict__ out, int n)
{
    const int i = (blockIdx.x * 256 + threadIdx.x) * 4;
    if (i >= n) return;
    const float4 v = *(const float4*)(in + i);
    out[i + 0] = (bf16)v.x; out[i + 1] = (bf16)v.y;
    out[i + 2] = (bf16)v.z; out[i + 3] = (bf16)v.w;
}

// w3 (1024 x 2730) fp32 -> (1024 x 2752) bf16 zero-padded
__global__ void conv_pad_w3(const float* __restrict__ w3, bf16* __restrict__ w3p)
{
    const int kk = blockIdx.x * 256 + threadIdx.x;
    const int row = blockIdx.y;
    if (kk >= FFNP) return;
    w3p[(size_t)row * FFNP + kk] = (kk < FFN_) ? (bf16)w3[(size_t)row * FFN_ + kk] : (bf16)0.f;
}

// ---------------------------------------------------------------- GEMM (m97 structure)
// C[M x Nreal] = A[M x K] * Bm[Nreal x K]^T (+bias), tile 128x128, BK=32
__global__ __launch_bounds__(256) void gemm_bt(
    const bf16* __restrict__ A, const bf16* __restrict__ Bm, const float* __restrict__ bias,
    int K, int Nreal, int epi,
    bf16* __restrict__ outb, int ldo,
    bf16* __restrict__ qo, bf16* __restrict__ ko, bf16* __restrict__ vo,
    float* __restrict__ hres, const float* __restrict__ gate, int gstride)
{
    __shared__ __align__(16) bf16 As[128 * 32];
    __shared__ __align__(16) bf16 Bs[128 * 32];
    const int t    = threadIdx.x;
    const int M0   = blockIdx.y * 128;
    const int N0   = blockIdx.x * 128;
    const int lane = t & 63;
    const int w    = t >> 6;
    const int wr   = (w >> 1) * 64, wc = (w & 1) * 64;
    const int quad = lane >> 4, r16 = lane & 15;
    const int sr   = t >> 2;          // staging row 0..63
    const int sk   = (t & 3) * 8;     // staging k-offset (elements)
    const int Nlast = Nreal - 1;

    floatx4 acc[4][4];
    const floatx4 zero = {0.f, 0.f, 0.f, 0.f};
    #pragma unroll
    for (int i = 0; i < 4; i++)
        #pragma unroll
        for (int j = 0; j < 4; j++) acc[i][j] = zero;

    for (int k0 = 0; k0 < K; k0 += 32) {
        const bf16* ga0 = A + (size_t)(M0 + sr) * K + k0 + sk;
        const bf16* ga1 = A + (size_t)(M0 + sr + 64) * K + k0 + sk;
        int n0c = N0 + sr;      if (n0c > Nlast) n0c = Nlast;
        int n1c = N0 + sr + 64; if (n1c > Nlast) n1c = Nlast;
        const bf16* gb0 = Bm + (size_t)n0c * K + k0 + sk;
        const bf16* gb1 = Bm + (size_t)n1c * K + k0 + sk;
        __builtin_amdgcn_global_load_lds((const __attribute__((address_space(1))) void*)ga0,
            (__attribute__((address_space(3))) void*)(As + t * 8), 16, 0, 0);
        __builtin_amdgcn_global_load_lds((const __attribute__((address_space(1))) void*)ga1,
            (__attribute__((address_space(3))) void*)(As + (t + 256) * 8), 16, 0, 0);
        __builtin_amdgcn_global_load_lds((const __attribute__((address_space(1))) void*)gb0,
            (__attribute__((address_space(3))) void*)(Bs + t * 8), 16, 0, 0);
        __builtin_amdgcn_global_load_lds((const __attribute__((address_space(1))) void*)gb1,
            (__attribute__((address_space(3))) void*)(Bs + (t + 256) * 8), 16, 0, 0);
        __syncthreads();
        bf16x8 af[4], bfv[4];
        #pragma unroll
        for (int i = 0; i < 4; i++) af[i]  = *(const bf16x8*)(As + (wr + i * 16 + r16) * 32 + quad * 8);
        #pragma unroll
        for (int j = 0; j < 4; j++) bfv[j] = *(const bf16x8*)(Bs + (wc + j * 16 + r16) * 32 + quad * 8);
        #pragma unroll
        for (int i = 0; i < 4; i++)
            #pragma unroll
            for (int j = 0; j < 4; j++)
                acc[i][j] = __builtin_amdgcn_mfma_f32_16x16x32_bf16(af[i], bfv[j], acc[i][j], 0, 0, 0);
        __syncthreads();
    }

    // epilogue: D row = quad*4+rr (within 16-tile), col = r16   [verified m89/m91]
    #pragma unroll
    for (int i = 0; i < 4; i++) {
        const int rbase = M0 + wr + i * 16 + quad * 4;
        #pragma unroll
        for (int j = 0; j < 4; j++) {
            const int col = N0 + wc + j * 16 + r16;
            if (col >= Nreal) continue;
            const float bv = bias[col];
            if (epi == EPI_BF16) {
                #pragma unroll
                for (int rr = 0; rr < 4; rr++) {
                    const int row = rbase + rr;
                    outb[(size_t)row * ldo + col] = (bf16)(acc[i][j][rr] + bv);
                }
            } else if (epi == EPI_QKV) {
                const int s = col >> 10, hh = (col >> 6) & 15, dd = col & 63;
                bf16* dst = (s == 0) ? qo : (s == 1) ? ko : vo;
                #pragma unroll
                for (int rr = 0; rr < 4; rr++) {
                    const int row = rbase + rr;
                    const int b = row >> 10, n = row & 1023;
                    dst[((size_t)(b * 16 + hh) * 1024 + n) * 64 + dd] = (bf16)(acc[i][j][rr] + bv);
                }
            } else { // EPI_RESID: h += gate * (acc + bias)
                #pragma unroll
                for (int rr = 0; rr < 4; rr++) {
                    const int row = rbase + rr;
                    const int b = row >> 10;
                    hres[(size_t)row * 1024 + col] += gate[(size_t)b * gstride + col] * (acc[i][j][rr] + bv);
                }
            }
        }
    }
}

// ---------------------------------------------------------------- small GEMM (8 x N) = A(8 x K) * W(N x K)^T
// mode 0: A = fp32 ws (stride 1024). mode 1: A = timestep embedding from t (K=256).
__global__ __launch_bounds__(256) void small_gemm(
    const float* __restrict__ Aws, const float* __restrict__ t_in,
    const float* __restrict__ W, const float* __restrict__ bias,
    float* __restrict__ out, int N, int K, int mode, int dosilu)
{
    const int w = threadIdx.x >> 6, lane = threadIdx.x & 63;
    const int col = blockIdx.x * 4 + w;
    float acc[8];
    #pragma unroll
    for (int bb = 0; bb < 8; bb++) acc[bb] = 0.f;
    float tb[8];
    if (mode == 1) {
        #pragma unroll
        for (int bb = 0; bb < 8; bb++) tb[bb] = t_in[bb];
    }
    for (int kk = lane; kk < K; kk += 64) {
        const float wv = W[(size_t)col * K + kk];
        if (mode == 1) {
            const float f = __expf(-(float)(kk & 127) * (9.21034037198f / 128.f));
            #pragma unroll
            for (int bb = 0; bb < 8; bb++) {
                const float arg = tb[bb] * f;
                const float e = (kk < 128) ? cosf(arg) : sinf(arg);
                acc[bb] += e * wv;
            }
        } else {
            #pragma unroll
            for (int bb = 0; bb < 8; bb++) acc[bb] += Aws[(size_t)bb * 1024 + kk] * wv;
        }
    }
    #pragma unroll
    for (int bb = 0; bb < 8; bb++) {
        float v2 = acc[bb];
        #pragma unroll
        for (int off = 32; off; off >>= 1) v2 += __shfl_xor(v2, off, 64);
        acc[bb] = v2;
    }
    if (lane == 0) {
        const float bv = bias[col];
        #pragma unroll
        for (int bb = 0; bb < 8; bb++) {
            float vv = acc[bb] + bv;
            if (dosilu) vv = vv / (1.f + __expf(-vv));
            out[(size_t)bb * N + col] = vv;
        }
    }
}

// ---------------------------------------------------------------- patch embed + pos embed -> h (fp32)
__global__ __launch_bounds__(256) void patch_embed(
    const float* __restrict__ x, const float* __restrict__ pw, const float* __restrict__ pb,
    float* __restrict__ h)
{
    __shared__ float xs[32];
    const int row = blockIdx.x, t = threadIdx.x;
    const int b = row >> 10, n = row & 1023;
    const int hp = n >> 4, wp = n & 15;
    if (t < 32) {
        const int c = t >> 4, ph = (t >> 2) & 3, pq = t & 3;
        xs[t] = x[((size_t)(b * 2 + c) * 256 + hp * 4 + ph) * 64 + wp * 4 + pq];
    }
    __syncthreads();
    #pragma unroll
    for (int rep = 0; rep < 4; rep++) {
        const int o = t + rep * 256;
        const float* wrow = pw + (size_t)o * 32;
        float acc = pb[o];
        #pragma unroll
        for (int e = 0; e < 32; e++) acc += xs[e] * wrow[e];
        // pos embed: [0:256) sin(wp*om) [256:512) cos(wp*om) [512:768) sin(hp*om) [768:1024) cos(hp*om)
        const int seg = o >> 8, oo = o & 255;
        const float om = __expf(-(float)oo * (9.21034037198f / 256.f));
        const float pos = (seg < 2) ? (float)wp : (float)hp;
        const float arg = pos * om;
        const float pe = ((seg & 1) == 0) ? sinf(arg) : cosf(arg);
        h[(size_t)row * 1024 + o] = acc + pe;
    }
}

// ---------------------------------------------------------------- rmsnorm + modulate -> bf16
__global__ __launch_bounds__(256) void norm_mod(
    const float* __restrict__ h, const float* __restrict__ w,
    const float* __restrict__ ada, int sh_off, int sc_off, int stride,
    bf16* __restrict__ out)
{
    __shared__ float red[4];
    const int row = blockIdx.x, t = threadIdx.x;
    const int b = row >> 10;
    const float4 xv = ((const float4*)(h + (size_t)row * 1024))[t];
    float ss = xv.x * xv.x + xv.y * xv.y + xv.z * xv.z + xv.w * xv.w;
    #pragma unroll
    for (int off = 32; off; off >>= 1) ss += __shfl_xor(ss, off, 64);
    if ((t & 63) == 0) red[t >> 6] = ss;
    __syncthreads();
    const float total = red[0] + red[1] + red[2] + red[3];
    const float rms = rsqrtf(total * (1.f / 1024.f) + 1e-6f);
    const float* sh = ada + (size_t)b * stride + sh_off;
    const float* sc = ada + (size_t)b * stride + sc_off;
    const float vals[4] = {xv.x, xv.y, xv.z, xv.w};
    #pragma unroll
    for (int e = 0; e < 4; e++) {
        const int c2 = t * 4 + e;
        const float vv = vals[e] * rms * w[c2] * (1.f + sc[c2]) + sh[c2];
        out[(size_t)row * 1024 + c2] = (bf16)vv;
    }
}

// ---------------------------------------------------------------- qk rmsnorm + RoPE (in place)
__global__ __launch_bounds__(64) void rope_qk(
    bf16* __restrict__ q, bf16* __restrict__ k,
    const float* __restrict__ qw, const float* __restrict__ kw)
{
    const int n = blockIdx.x, bh = blockIdx.y, d = threadIdx.x;
    const size_t idx = ((size_t)bh * 1024 + n) * 64 + d;
    const float qv = (float)q[idx], kv = (float)k[idx];
    float sq = qv * qv, sk = kv * kv;
    #pragma unroll
    for (int off = 32; off; off >>= 1) { sq += __shfl_xor(sq, off, 64); sk += __shfl_xor(sk, off, 64); }
    const float rq = rsqrtf(sq * (1.f / 64.f) + 1e-6f);
    const float rk = rsqrtf(sk * (1.f / 64.f) + 1e-6f);
    const float qn = qv * rq * qw[d];
    const float kn = kv * rk * kw[d];
    const int j = (d & 31) >> 1;
    const float freq = __expf(-(float)j * (9.21034037198f / 16.f));   // 10000^(-j/16)
    const float pos = (d < 32) ? (float)(n >> 4) : (float)(n & 15);
    const float ang = pos * freq;
    const float cv = cosf(ang), sv = sinf(ang);
    const float qp = __shfl_xor(qn, 1, 64);
    const float kp = __shfl_xor(kn, 1, 64);
    const float qo = qn * cv + ((d & 1) ? qp : -qp) * sv;
    const float ko = kn * cv + ((d & 1) ? kp : -kp) * sv;
    q[idx] = (bf16)qo;
    k[idx] = (bf16)ko;
}

// ---------------------------------------------------------------- fused flash attention
// grid (16 qtiles, 128 bh), 256 threads. Qtile=64, Ktile=64, HD=64.
__global__ __launch_bounds__(256) void attn_kernel(
    const bf16* __restrict__ q, const bf16* __restrict__ k, const bf16* __restrict__ v,
    bf16* __restrict__ o)
{
    __shared__ float Qs[64 * 68];
    __shared__ float Ks[64 * 68];   // aliased as P^T after S phase
    __shared__ float Vs[64 * 68];
    const int t = threadIdx.x, tx = t & 15, ty = t >> 4;
    const int qt = blockIdx.x, bh = blockIdx.y;
    const int b = bh >> 4, hh = bh & 15;
    const int sr = t >> 2, sd = (t & 3) * 16;
    {
        const bf16* src = q + ((size_t)bh * 1024 + qt * 64 + sr) * 64 + sd;
        const bf16x8 a0 = *(const bf16x8*)src;
        const bf16x8 a1 = *(const bf16x8*)(src + 8);
        #pragma unroll
        for (int e = 0; e < 8; e++) {
            Qs[sr * 68 + sd + e]     = (float)a0[e];
            Qs[sr * 68 + sd + 8 + e] = (float)a1[e];
        }
    }
    float mrow[4], lrow[4], oacc[4][4];
    #pragma unroll
    for (int i = 0; i < 4; i++) {
        mrow[i] = -1e30f; lrow[i] = 0.f;
        #pragma unroll
        for (int c = 0; c < 4; c++) oacc[i][c] = 0.f;
    }
    for (int kt = 0; kt < 16; kt++) {
        __syncthreads();  // protect Ks(PT)/Vs from previous iter readers
        {
            const bf16* ks = k + ((size_t)bh * 1024 + kt * 64 + sr) * 64 + sd;
            const bf16* vs = v + ((size_t)bh * 1024 + kt * 64 + sr) * 64 + sd;
            const bf16x8 a0 = *(const bf16x8*)ks; const bf16x8 a1 = *(const bf16x8*)(ks + 8);
            const bf16x8 b0 = *(const bf16x8*)vs; const bf16x8 b1 = *(const bf16x8*)(vs + 8);
            #pragma unroll
            for (int e = 0; e < 8; e++) {
                Ks[sr * 68 + sd + e]     = (float)a0[e];
                Ks[sr * 68 + sd + 8 + e] = (float)a1[e];
                Vs[sr * 68 + sd + e]     = (float)b0[e];
                Vs[sr * 68 + sd + 8 + e] = (float)b1[e];
            }
        }
        __syncthreads();
        float s[4][4];
        #pragma unroll
        for (int i = 0; i < 4; i++)
            #pragma unroll
            for (int j = 0; j < 4; j++) s[i][j] = 0.f;
        for (int dd = 0; dd < 64; dd += 4) {
            float4 qv[4], kv[4];
            #pragma unroll
            for (int i = 0; i < 4; i++) qv[i] = *(const float4*)&Qs[(ty * 4 + i) * 68 + dd];
            #pragma unroll
            for (int j = 0; j < 4; j++) kv[j] = *(const float4*)&Ks[(tx * 4 + j) * 68 + dd];
            #pragma unroll
            for (int i = 0; i < 4; i++)
                #pragma unroll
                for (int j = 0; j < 4; j++)
                    s[i][j] += qv[i].x * kv[j].x + qv[i].y * kv[j].y + qv[i].z * kv[j].z + qv[i].w * kv[j].w;
        }
        float al[4];
        #pragma unroll
        for (int i = 0; i < 4; i++) {
            #pragma unroll
            for (int j = 0; j < 4; j++) s[i][j] *= 0.125f;   // 1/sqrt(64)
            float mx = fmaxf(fmaxf(s[i][0], s[i][1]), fmaxf(s[i][2], s[i][3]));
            #pragma unroll
            for (int off = 1; off < 16; off <<= 1) mx = fmaxf(mx, __shfl_xor(mx, off, 64));
            const float mn = fmaxf(mrow[i], mx);
            float ps = 0.f;
            #pragma unroll
            for (int j = 0; j < 4; j++) { s[i][j] = __expf(s[i][j] - mn); ps += s[i][j]; }
            #pragma unroll
            for (int off = 1; off < 16; off <<= 1) ps += __shfl_xor(ps, off, 64);
            al[i] = __expf(mrow[i] - mn);
            lrow[i] = lrow[i] * al[i] + ps;
            mrow[i] = mn;
        }
        __syncthreads();  // all waves done reading Ks
        float* PT = Ks;
        #pragma unroll
        for (int i = 0; i < 4; i++)
            #pragma unroll
            for (int j = 0; j < 4; j++)
                PT[(tx * 4 + j) * 68 + ty * 4 + i] = s[i][j];
        __syncthreads();
        #pragma unroll
        for (int i = 0; i < 4; i++)
            #pragma unroll
            for (int c = 0; c < 4; c++) oacc[i][c] *= al[i];
        for (int j = 0; j < 64; j++) {
            const float4 vv = *(const float4*)&Vs[j * 68 + tx * 4];
            const float4 pp = *(const float4*)&PT[j * 68 + ty * 4];
            oacc[0][0] += pp.x * vv.x; oacc[0][1] += pp.x * vv.y; oacc[0][2] += pp.x * vv.z; oacc[0][3] += pp.x * vv.w;
            oacc[1][0] += pp.y * vv.x; oacc[1][1] += pp.y * vv.y; oacc[1][2] += pp.y * vv.z; oacc[1][3] += pp.y * vv.w;
            oacc[2][0] += pp.z * vv.x; oacc[2][1] += pp.z * vv.y; oacc[2][2] += pp.z * vv.z; oacc[2][3] += pp.z * vv.w;
            oacc[3][0] += pp.w * vv.x; oacc[3][1] += pp.w * vv.y; oacc[3][2] += pp.w * vv.z; oacc[3][3] += pp.w * vv.w;
        }
    }
    #pragma unroll
    for (int i = 0; i < 4; i++) {
        const float inv = 1.f / lrow[i];
        const size_t base = ((size_t)b * 1024 + qt * 64 + ty * 4 + i) * 1024 + hh * 64 + tx * 4;
        #pragma unroll
        for (int c = 0; c < 4; c++) o[base + c] = (bf16)(oacc[i][c] * inv);
    }
}

// ---------------------------------------------------------------- swiglu: g = silu(x1)*x2, K-padded to 2752 w/ zeros
__global__ void swiglu_kernel(const bf16* __restrict__ x12, bf16* __restrict__ g)
{
    const int kk = blockIdx.x * 256 + threadIdx.x;
    const int row = blockIdx.y;
    if (kk >= FFNP) return;
    float gv = 0.f;
    if (kk < FFN_) {
        const float a  = (float)x12[(size_t)row * X12N + kk];
        const float b2 = (float)x12[(size_t)row * X12N + FFN_ + kk];
        gv = a * b2 / (1.f + __expf(-a));
    }
    g[(size_t)row * FFNP + kk] = (bf16)gv;
}

// ---------------------------------------------------------------- final linear (K=1024 -> 32) + unpatchify
__global__ __launch_bounds__(256) void final_head(
    const bf16* __restrict__ hn, const float* __restrict__ fw, const float* __restrict__ fb,
    float* __restrict__ out)
{
    __shared__ float hs[1024];
    const int row = blockIdx.x, t = threadIdx.x;
    #pragma unroll
    for (int r = 0; r < 4; r++) hs[t + r * 256] = (float)hn[(size_t)row * 1024 + t + r * 256];
    __syncthreads();
    const int o = t >> 3, s = t & 7;
    float acc = 0.f;
    const float* wr = fw + (size_t)o * 1024 + s * 128;
    const float* hb = hs + s * 128;
    for (int e = 0; e < 128; e++) acc += hb[e] * wr[e];
    #pragma unroll
    for (int off = 1; off < 8; off <<= 1) acc += __shfl_xor(acc, off, 64);
    if (s == 0) {
        acc += fb[o];
        const int b = row >> 10, n = row & 1023;
        const int hp = n >> 4, wp = n & 15;
        const int ph = o >> 3, pw = (o >> 1) & 3, c = o & 1;
        out[((size_t)(b * 2 + c) * 256 + hp * 4 + ph) * 64 + wp * 4 + pw] = acc;
    }
}

// ================================================================ launch
extern "C" void kernel_launch(void* const* d_in, const int* in_sizes, int n_in,
                              void* d_out, int out_size, void* d_ws, size_t ws_size,
                              hipStream_t stream)
{
    const float* x       = (const float*)d_in[0];
    const float* t_in    = (const float*)d_in[1];
    const float* patch_w = (const float*)d_in[2];
    const float* patch_b = (const float*)d_in[3];
    const float* t_w     = (const float*)d_in[4];
    const float* t_b     = (const float*)d_in[5];
    const float* norm1_w = (const float*)d_in[6];
    const float* qkv_w   = (const float*)d_in[7];
    const float* qkv_b   = (const float*)d_in[8];
    const float* qn_w    = (const float*)d_in[9];
    const float* kn_w    = (const float*)d_in[10];
    const float* proj_w  = (const float*)d_in[11];
    const float* proj_b  = (const float*)d_in[12];
    const float* norm2_w = (const float*)d_in[13];
    const float* w12_w   = (const float*)d_in[14];
    const float* w12_b   = (const float*)d_in[15];
    const float* w3_w    = (const float*)d_in[16];
    const float* w3_b    = (const float*)d_in[17];
    const float* ada_w   = (const float*)d_in[18];
    const float* ada_b   = (const float*)d_in[19];
    const float* fnorm_w = (const float*)d_in[20];
    const float* flin_w  = (const float*)d_in[21];
    const float* flin_b  = (const float*)d_in[22];
    const float* fada_w  = (const float*)d_in[23];
    const float* fada_b  = (const float*)d_in[24];

    char* ws = (char*)d_ws;
    size_t off = 0;
    auto alloc = [&](size_t nbytes) { char* p = ws + off; off += (nbytes + 255) & ~(size_t)255; return p; };
    float* h     = (float*)alloc((size_t)TOKS * 1024 * 4);    // residual stream fp32
    float* cs    = (float*)alloc(8 * 1024 * 4);               // silu(t-emb)
    float* ada   = (float*)alloc(8 * 6144 * 4);
    float* fada  = (float*)alloc(8 * 2048 * 4);
    bf16*  hn    = (bf16*)alloc((size_t)TOKS * 1024 * 2);
    char*  U1    =         alloc((size_t)TOKS * X12N * 2);    // q,k,v,o during attn; x12 during FFN
    bf16*  qb    = (bf16*)U1;
    bf16*  kb    = qb + (size_t)TOKS * 1024;
    bf16*  vb    = kb + (size_t)TOKS * 1024;
    bf16*  ob    = vb + (size_t)TOKS * 1024;
    bf16*  x12   = (bf16*)U1;
    bf16*  g     = (bf16*)alloc((size_t)TOKS * FFNP * 2);
    bf16*  wqkvb = (bf16*)alloc((size_t)3072 * 1024 * 2);
    bf16*  wprjb = (bf16*)alloc((size_t)1024 * 1024 * 2);
    bf16*  w12b  = (bf16*)alloc((size_t)X12N * 1024 * 2);
    bf16*  w3p   = (bf16*)alloc((size_t)1024 * FFNP * 2);
    (void)ws_size; (void)in_sizes; (void)n_in; (void)out_size;

    // timestep embedding -> cs = silu(emb @ t_w^T + t_b)
    small_gemm<<<dim3(1024 / 4), 256, 0, stream>>>(nullptr, t_in, t_w, t_b, cs, 1024, 256, 1, 1);
    // patch embed + pos -> h
    patch_embed<<<dim3(TOKS), 256, 0, stream>>>(x, patch_w, patch_b, h);

    for (int d = 0; d < 8; d++) {
        small_gemm<<<dim3(6144 / 4), 256, 0, stream>>>(cs, nullptr,
            ada_w + (size_t)d * 6144 * 1024, ada_b + (size_t)d * 6144, ada, 6144, 1024, 0, 0);
        norm_mod<<<dim3(TOKS), 256, 0, stream>>>(h, norm1_w + (size_t)d * 1024, ada, 0, 1024, 6144, hn);
        conv_bf16<<<dim3(3072 * 1024 / 4 / 256), 256, 0, stream>>>(qkv_w + (size_t)d * 3072 * 1024, wqkvb, 3072 * 1024);
        gemm_bt<<<dim3(3072 / 128, 64), 256, 0, stream>>>(hn,
            wqkvb, qkv_b + (size_t)d * 3072, 1024, 3072, EPI_QKV,
            nullptr, 0, qb, kb, vb, nullptr, nullptr, 0);
        rope_qk<<<dim3(1024, 128), 64, 0, stream>>>(qb, kb, qn_w + (size_t)d * 64, kn_w + (size_t)d * 64);
        attn_kernel<<<dim3(16, 128), 256, 0, stream>>>(qb, kb, vb, ob);
        conv_bf16<<<dim3(1024 * 1024 / 4 / 256), 256, 0, stream>>>(proj_w + (size_t)d * 1024 * 1024, wprjb, 1024 * 1024);
        gemm_bt<<<dim3(1024 / 128, 64), 256, 0, stream>>>(ob,
            wprjb, proj_b + (size_t)d * 1024, 1024, 1024, EPI_RESID,
            nullptr, 0, nullptr, nullptr, nullptr, h, ada + 2048, 6144);
        norm_mod<<<dim3(TOKS), 256, 0, stream>>>(h, norm2_w + (size_t)d * 1024, ada, 3072, 4096, 6144, hn);
        conv_bf16<<<dim3(X12N * 1024 / 4 / 256), 256, 0, stream>>>(w12_w + (size_t)d * X12N * 1024, w12b, X12N * 1024);
        gemm_bt<<<dim3(43, 64), 256, 0, stream>>>(hn,
            w12b, w12_b + (size_t)d * X12N, 1024, X12N, EPI_BF16,
            x12, X12N, nullptr, nullptr, nullptr, nullptr, nullptr, 0);
        swiglu_kernel<<<dim3(11, TOKS), 256, 0, stream>>>(x12, g);
        conv_pad_w3<<<dim3(11, 1024), 256, 0, stream>>>(w3_w + (size_t)d * 1024 * FFN_, w3p);
        gemm_bt<<<dim3(1024 / 128, 64), 256, 0, stream>>>(g,
            w3p, w3_b + (size_t)d * 1024, FFNP, 1024, EPI_RESID,
            nullptr, 0, nullptr, nullptr, nullptr, h, ada + 5120, 6144);
    }

    small_gemm<<<dim3(2048 / 4), 256, 0, stream>>>(cs, nullptr, fada_w, fada_b, fada, 2048, 1024, 0, 0);
    norm_mod<<<dim3(TOKS), 256, 0, stream>>>(h, fnorm_w, fada, 0, 1024, 2048, hn);
    final_head<<<dim3(TOKS), 256, 0, stream>>>(hn, flin_w, flin_b, (float*)d_out);
}

// Round 3
// 5498.500 us; speedup vs baseline: 1.6295x; 1.6295x over previous
//
#include <hip/hip_runtime.h>
#include <stdint.h>

typedef __bf16 bf16;
typedef __attribute__((ext_vector_type(8))) __bf16 bf16x8;
typedef __attribute__((ext_vector_type(4))) float floatx4;

#define NTOK   1024     // tokens per batch (N)
#define TOKS   8192     // B*N
#define HID_   1024
#define FFN_   2730
#define FFNP   2752     // FFN padded to mult of 32
#define X12N   5460     // 2*FFN

#define EPI_BF16  0
#define EPI_QKV   1
#define EPI_RESID 2

// ---------------------------------------------------------------- fp32 -> bf16 weight conversion
__global__ __launch_bounds__(256) void conv_bf16(const float* __restrict__ in, bf16* __restrict__ out, int n)
{
    const int i = (blockIdx.x * 256 + threadIdx.x) * 4;
    if (i >= n) return;
    const float4 v = *(const float4*)(in + i);
    out[i + 0] = (bf16)v.x; out[i + 1] = (bf16)v.y;
    out[i + 2] = (bf16)v.z; out[i + 3] = (bf16)v.w;
}

// w3 (1024 x 2730) fp32 -> (1024 x 2752) bf16 zero-padded
__global__ void conv_pad_w3(const float* __restrict__ w3, bf16* __restrict__ w3p)
{
    const int kk = blockIdx.x * 256 + threadIdx.x;
    const int row = blockIdx.y;
    if (kk >= FFNP) return;
    w3p[(size_t)row * FFNP + kk] = (kk < FFN_) ? (bf16)w3[(size_t)row * FFN_ + kk] : (bf16)0.f;
}

// ---------------------------------------------------------------- GEMM (m97 structure)
// C[M x Nreal] = A[M x K] * Bm[Nreal x K]^T (+bias), tile 128x128, BK=32
__global__ __launch_bounds__(256) void gemm_bt(
    const bf16* __restrict__ A, const bf16* __restrict__ Bm, const float* __restrict__ bias,
    int K, int Nreal, int epi,
    bf16* __restrict__ outb, int ldo,
    bf16* __restrict__ qo, bf16* __restrict__ ko, bf16* __restrict__ vo,
    float* __restrict__ hres, const float* __restrict__ gate, int gstride)
{
    __shared__ __align__(16) bf16 As[128 * 32];
    __shared__ __align__(16) bf16 Bs[128 * 32];
    const int t    = threadIdx.x;
    const int M0   = blockIdx.y * 128;
    const int N0   = blockIdx.x * 128;
    const int lane = t & 63;
    const int w    = t >> 6;
    const int wr   = (w >> 1) * 64, wc = (w & 1) * 64;
    const int quad = lane >> 4, r16 = lane & 15;
    const int sr   = t >> 2;          // staging row 0..63
    const int sk   = (t & 3) * 8;     // staging k-offset (elements)
    const int Nlast = Nreal - 1;

    floatx4 acc[4][4];
    const floatx4 zero = {0.f, 0.f, 0.f, 0.f};
    #pragma unroll
    for (int i = 0; i < 4; i++)
        #pragma unroll
        for (int j = 0; j < 4; j++) acc[i][j] = zero;

    for (int k0 = 0; k0 < K; k0 += 32) {
        const bf16* ga0 = A + (size_t)(M0 + sr) * K + k0 + sk;
        const bf16* ga1 = A + (size_t)(M0 + sr + 64) * K + k0 + sk;
        int n0c = N0 + sr;      if (n0c > Nlast) n0c = Nlast;
        int n1c = N0 + sr + 64; if (n1c > Nlast) n1c = Nlast;
        const bf16* gb0 = Bm + (size_t)n0c * K + k0 + sk;
        const bf16* gb1 = Bm + (size_t)n1c * K + k0 + sk;
        __builtin_amdgcn_global_load_lds((const __attribute__((address_space(1))) void*)ga0,
            (__attribute__((address_space(3))) void*)(As + t * 8), 16, 0, 0);
        __builtin_amdgcn_global_load_lds((const __attribute__((address_space(1))) void*)ga1,
            (__attribute__((address_space(3))) void*)(As + (t + 256) * 8), 16, 0, 0);
        __builtin_amdgcn_global_load_lds((const __attribute__((address_space(1))) void*)gb0,
            (__attribute__((address_space(3))) void*)(Bs + t * 8), 16, 0, 0);
        __builtin_amdgcn_global_load_lds((const __attribute__((address_space(1))) void*)gb1,
            (__attribute__((address_space(3))) void*)(Bs + (t + 256) * 8), 16, 0, 0);
        __syncthreads();
        bf16x8 af[4], bfv[4];
        #pragma unroll
        for (int i = 0; i < 4; i++) af[i]  = *(const bf16x8*)(As + (wr + i * 16 + r16) * 32 + quad * 8);
        #pragma unroll
        for (int j = 0; j < 4; j++) bfv[j] = *(const bf16x8*)(Bs + (wc + j * 16 + r16) * 32 + quad * 8);
        #pragma unroll
        for (int i = 0; i < 4; i++)
            #pragma unroll
            for (int j = 0; j < 4; j++)
                acc[i][j] = __builtin_amdgcn_mfma_f32_16x16x32_bf16(af[i], bfv[j], acc[i][j], 0, 0, 0);
        __syncthreads();
    }

    // epilogue: D row = quad*4+rr (within 16-tile), col = r16   [verified m89/m91]
    #pragma unroll
    for (int i = 0; i < 4; i++) {
        const int rbase = M0 + wr + i * 16 + quad * 4;
        #pragma unroll
        for (int j = 0; j < 4; j++) {
            const int col = N0 + wc + j * 16 + r16;
            if (col >= Nreal) continue;
            const float bv = bias[col];
            if (epi == EPI_BF16) {
                #pragma unroll
                for (int rr = 0; rr < 4; rr++) {
                    const int row = rbase + rr;
                    outb[(size_t)row * ldo + col] = (bf16)(acc[i][j][rr] + bv);
                }
            } else if (epi == EPI_QKV) {
                const int s = col >> 10, hh = (col >> 6) & 15, dd = col & 63;
                #pragma unroll
                for (int rr = 0; rr < 4; rr++) {
                    const int row = rbase + rr;
                    const int b = row >> 10, n = row & 1023;
                    const float vv = acc[i][j][rr] + bv;
                    if (s == 0)      qo[((size_t)(b * 16 + hh) * 1024 + n) * 64 + dd] = (bf16)vv;
                    else if (s == 1) ko[((size_t)(b * 16 + hh) * 1024 + n) * 64 + dd] = (bf16)vv;
                    else             vo[((size_t)(b * 16 + hh) * 64 + dd) * 1024 + n] = (bf16)vv;  // V^T: [bh][d][n]
                }
            } else { // EPI_RESID: h += gate * (acc + bias)
                #pragma unroll
                for (int rr = 0; rr < 4; rr++) {
                    const int row = rbase + rr;
                    const int b = row >> 10;
                    hres[(size_t)row * 1024 + col] += gate[(size_t)b * gstride + col] * (acc[i][j][rr] + bv);
                }
            }
        }
    }
}

// ---------------------------------------------------------------- small GEMM (8 x N) = A(8 x K) * W(N x K)^T
__global__ __launch_bounds__(256) void small_gemm(
    const float* __restrict__ Aws, const float* __restrict__ t_in,
    const float* __restrict__ W, const float* __restrict__ bias,
    float* __restrict__ out, int N, int K, int mode, int dosilu)
{
    const int w = threadIdx.x >> 6, lane = threadIdx.x & 63;
    const int col = blockIdx.x * 4 + w;
    float acc[8];
    #pragma unroll
    for (int bb = 0; bb < 8; bb++) acc[bb] = 0.f;
    float tb[8];
    if (mode == 1) {
        #pragma unroll
        for (int bb = 0; bb < 8; bb++) tb[bb] = t_in[bb];
    }
    for (int kk = lane; kk < K; kk += 64) {
        const float wv = W[(size_t)col * K + kk];
        if (mode == 1) {
            const float f = __expf(-(float)(kk & 127) * (9.21034037198f / 128.f));
            #pragma unroll
            for (int bb = 0; bb < 8; bb++) {
                const float arg = tb[bb] * f;
                const float e = (kk < 128) ? cosf(arg) : sinf(arg);
                acc[bb] += e * wv;
            }
        } else {
            #pragma unroll
            for (int bb = 0; bb < 8; bb++) acc[bb] += Aws[(size_t)bb * 1024 + kk] * wv;
        }
    }
    #pragma unroll
    for (int bb = 0; bb < 8; bb++) {
        float v2 = acc[bb];
        #pragma unroll
        for (int off = 32; off; off >>= 1) v2 += __shfl_xor(v2, off, 64);
        acc[bb] = v2;
    }
    if (lane == 0) {
        const float bv = bias[col];
        #pragma unroll
        for (int bb = 0; bb < 8; bb++) {
            float vv = acc[bb] + bv;
            if (dosilu) vv = vv / (1.f + __expf(-vv));
            out[(size_t)bb * N + col] = vv;
        }
    }
}

// ---------------------------------------------------------------- patch embed + pos embed -> h (fp32)
__global__ __launch_bounds__(256) void patch_embed(
    const float* __restrict__ x, const float* __restrict__ pw, const float* __restrict__ pb,
    float* __restrict__ h)
{
    __shared__ float xs[32];
    const int row = blockIdx.x, t = threadIdx.x;
    const int b = row >> 10, n = row & 1023;
    const int hp = n >> 4, wp = n & 15;
    if (t < 32) {
        const int c = t >> 4, ph = (t >> 2) & 3, pq = t & 3;
        xs[t] = x[((size_t)(b * 2 + c) * 256 + hp * 4 + ph) * 64 + wp * 4 + pq];
    }
    __syncthreads();
    #pragma unroll
    for (int rep = 0; rep < 4; rep++) {
        const int o = t + rep * 256;
        const float* wrow = pw + (size_t)o * 32;
        float acc = pb[o];
        #pragma unroll
        for (int e = 0; e < 32; e++) acc += xs[e] * wrow[e];
        const int seg = o >> 8, oo = o & 255;
        const float om = __expf(-(float)oo * (9.21034037198f / 256.f));
        const float pos = (seg < 2) ? (float)wp : (float)hp;
        const float arg = pos * om;
        const float pe = ((seg & 1) == 0) ? sinf(arg) : cosf(arg);
        h[(size_t)row * 1024 + o] = acc + pe;
    }
}

// ---------------------------------------------------------------- rmsnorm + modulate -> bf16
__global__ __launch_bounds__(256) void norm_mod(
    const float* __restrict__ h, const float* __restrict__ w,
    const float* __restrict__ ada, int sh_off, int sc_off, int stride,
    bf16* __restrict__ out)
{
    __shared__ float red[4];
    const int row = blockIdx.x, t = threadIdx.x;
    const int b = row >> 10;
    const float4 xv = ((const float4*)(h + (size_t)row * 1024))[t];
    float ss = xv.x * xv.x + xv.y * xv.y + xv.z * xv.z + xv.w * xv.w;
    #pragma unroll
    for (int off = 32; off; off >>= 1) ss += __shfl_xor(ss, off, 64);
    if ((t & 63) == 0) red[t >> 6] = ss;
    __syncthreads();
    const float total = red[0] + red[1] + red[2] + red[3];
    const float rms = rsqrtf(total * (1.f / 1024.f) + 1e-6f);
    const float* sh = ada + (size_t)b * stride + sh_off;
    const float* sc = ada + (size_t)b * stride + sc_off;
    const float vals[4] = {xv.x, xv.y, xv.z, xv.w};
    #pragma unroll
    for (int e = 0; e < 4; e++) {
        const int c2 = t * 4 + e;
        const float vv = vals[e] * rms * w[c2] * (1.f + sc[c2]) + sh[c2];
        out[(size_t)row * 1024 + c2] = (bf16)vv;
    }
}

// ---------------------------------------------------------------- qk rmsnorm + RoPE (in place)
__global__ __launch_bounds__(64) void rope_qk(
    bf16* __restrict__ q, bf16* __restrict__ k,
    const float* __restrict__ qw, const float* __restrict__ kw)
{
    const int n = blockIdx.x, bh = blockIdx.y, d = threadIdx.x;
    const size_t idx = ((size_t)bh * 1024 + n) * 64 + d;
    const float qv = (float)q[idx], kv = (float)k[idx];
    float sq = qv * qv, sk = kv * kv;
    #pragma unroll
    for (int off = 32; off; off >>= 1) { sq += __shfl_xor(sq, off, 64); sk += __shfl_xor(sk, off, 64); }
    const float rq = rsqrtf(sq * (1.f / 64.f) + 1e-6f);
    const float rk = rsqrtf(sk * (1.f / 64.f) + 1e-6f);
    const float qn = qv * rq * qw[d];
    const float kn = kv * rk * kw[d];
    const int j = (d & 31) >> 1;
    const float freq = __expf(-(float)j * (9.21034037198f / 16.f));   // 10000^(-j/16)
    const float pos = (d < 32) ? (float)(n >> 4) : (float)(n & 15);
    const float ang = pos * freq;
    const float cv = cosf(ang), sv = sinf(ang);
    const float qp = __shfl_xor(qn, 1, 64);
    const float kp = __shfl_xor(kn, 1, 64);
    const float qo = qn * cv + ((d & 1) ? qp : -qp) * sv;
    const float ko = kn * cv + ((d & 1) ? kp : -kp) * sv;
    q[idx] = (bf16)qo;
    k[idx] = (bf16)ko;
}

// ---------------------------------------------------------------- MFMA flash attention
// grid (16 qtiles, 128 bh), 256 threads = 4 waves; wave wq owns q rows wq*16..+15.
// q,k: [bh][n][64] bf16.  v: PRE-TRANSPOSED [bh][64][n] bf16.  o: [b][n][h*64+d].
__global__ __launch_bounds__(256) void attn_kernel(
    const bf16* __restrict__ q, const bf16* __restrict__ k, const bf16* __restrict__ v,
    bf16* __restrict__ o)
{
    __shared__ __align__(16) bf16 Qs[2 * 64 * 32];   // [half_d][row q][32]
    __shared__ __align__(16) bf16 Ks[2 * 64 * 32];   // [half_d][row ktok][32]
    __shared__ __align__(16) bf16 Vt[2 * 64 * 32];   // [half_ktok][row d][32]
    __shared__ __align__(16) bf16 Pw[4 * 16 * 80];   // per-wave P, row stride 80 (16B-aligned, 4-way max)
    const int t = threadIdx.x;
    const int l = t & 63, wq = t >> 6;
    const int quad = l >> 4, r16 = l & 15;
    const int qt = blockIdx.x, bh = blockIdx.y;
    const int b = bh >> 4, hh = bh & 15;

    // ---- stage Q (once): wave wq covers q rows wq*16..+15, 2 instrs for d halves
    #pragma unroll
    for (int m = 0; m < 2; m++) {
        const bf16* g = q + ((size_t)bh * 1024 + qt * 64 + wq * 16 + (l >> 2)) * 64 + m * 32 + (l & 3) * 8;
        __builtin_amdgcn_global_load_lds((const __attribute__((address_space(1))) void*)g,
            (__attribute__((address_space(3))) void*)(Qs + m * 2048 + wq * 16 * 32 + l * 8), 16, 0, 0);
    }
    __syncthreads();
    bf16x8 afq[2];
    #pragma unroll
    for (int h2 = 0; h2 < 2; h2++)
        afq[h2] = *(const bf16x8*)(Qs + h2 * 2048 + (wq * 16 + r16) * 32 + quad * 8);

    float m_r[4], l_r[4];
    floatx4 oacc[4];
    const floatx4 zero = {0.f, 0.f, 0.f, 0.f};
    #pragma unroll
    for (int rr = 0; rr < 4; rr++) { m_r[rr] = -1e30f; l_r[rr] = 0.f; }
    #pragma unroll
    for (int jd = 0; jd < 4; jd++) oacc[jd] = zero;

    bf16* Pme = Pw + wq * 16 * 80;

    for (int kt = 0; kt < 16; kt++) {
        __syncthreads();   // prev iter's Ks/Vt readers done
        #pragma unroll
        for (int m = 0; m < 2; m++) {
            const bf16* gk = k + ((size_t)bh * 1024 + kt * 64 + wq * 16 + (l >> 2)) * 64 + m * 32 + (l & 3) * 8;
            __builtin_amdgcn_global_load_lds((const __attribute__((address_space(1))) void*)gk,
                (__attribute__((address_space(3))) void*)(Ks + m * 2048 + wq * 16 * 32 + l * 8), 16, 0, 0);
            const bf16* gv = v + ((size_t)bh * 64 + wq * 16 + (l >> 2)) * 1024 + kt * 64 + m * 32 + (l & 3) * 8;
            __builtin_amdgcn_global_load_lds((const __attribute__((address_space(1))) void*)gv,
                (__attribute__((address_space(3))) void*)(Vt + m * 2048 + wq * 16 * 32 + l * 8), 16, 0, 0);
        }
        __syncthreads();   // staging visible (barrier drains vmcnt)

        // ---- S = Q K^T  (4 col-tiles of 16)
        floatx4 s[4];
        #pragma unroll
        for (int j = 0; j < 4; j++) {
            bf16x8 b0 = *(const bf16x8*)(Ks + 0 * 2048 + (j * 16 + r16) * 32 + quad * 8);
            bf16x8 b1 = *(const bf16x8*)(Ks + 1 * 2048 + (j * 16 + r16) * 32 + quad * 8);
            s[j] = __builtin_amdgcn_mfma_f32_16x16x32_bf16(afq[0], b0, zero, 0, 0, 0);
            s[j] = __builtin_amdgcn_mfma_f32_16x16x32_bf16(afq[1], b1, s[j], 0, 0, 0);
        }
        // ---- online softmax on C-layout (row=quad*4+rr, col=j*16+r16)
        float alpha[4];
        #pragma unroll
        for (int rr = 0; rr < 4; rr++) {
            float mx = fmaxf(fmaxf(s[0][rr], s[1][rr]), fmaxf(s[2][rr], s[3][rr])) * 0.125f;
            #pragma unroll
            for (int off2 = 1; off2 < 16; off2 <<= 1) mx = fmaxf(mx, __shfl_xor(mx, off2, 64));
            const float mn = fmaxf(m_r[rr], mx);
            float ps = 0.f;
            #pragma unroll
            for (int j = 0; j < 4; j++) {
                const float e = __expf(s[j][rr] * 0.125f - mn);
                s[j][rr] = e; ps += e;
            }
            #pragma unroll
            for (int off2 = 1; off2 < 16; off2 <<= 1) ps += __shfl_xor(ps, off2, 64);
            alpha[rr] = __expf(m_r[rr] - mn);
            l_r[rr] = l_r[rr] * alpha[rr] + ps;
            m_r[rr] = mn;
        }
        // ---- P -> wave-private LDS (C-layout write), read back as A-frags
        #pragma unroll
        for (int j = 0; j < 4; j++)
            #pragma unroll
            for (int rr = 0; rr < 4; rr++)
                Pme[(quad * 4 + rr) * 80 + j * 16 + r16] = (bf16)s[j][rr];
        __asm__ volatile("s_waitcnt lgkmcnt(0)" ::: "memory");
        bf16x8 afp[2];
        #pragma unroll
        for (int st = 0; st < 2; st++)
            afp[st] = *(const bf16x8*)(Pme + r16 * 80 + st * 32 + quad * 8);
        // ---- rescale O, then O += P V
        #pragma unroll
        for (int jd = 0; jd < 4; jd++)
            #pragma unroll
            for (int rr = 0; rr < 4; rr++) oacc[jd][rr] *= alpha[rr];
        #pragma unroll
        for (int jd = 0; jd < 4; jd++) {
            bf16x8 b0 = *(const bf16x8*)(Vt + 0 * 2048 + (jd * 16 + r16) * 32 + quad * 8);
            bf16x8 b1 = *(const bf16x8*)(Vt + 1 * 2048 + (jd * 16 + r16) * 32 + quad * 8);
            oacc[jd] = __builtin_amdgcn_mfma_f32_16x16x32_bf16(afp[0], b0, oacc[jd], 0, 0, 0);
            oacc[jd] = __builtin_amdgcn_mfma_f32_16x16x32_bf16(afp[1], b1, oacc[jd], 0, 0, 0);
        }
    }
    // ---- epilogue: o[b][n][h*64+d], row n = qt*64 + wq*16 + quad*4+rr, col d = jd*16+r16
    #pragma unroll
    for (int rr = 0; rr < 4; rr++) {
        const float inv = 1.f / l_r[rr];
        const size_t base = ((size_t)b * 1024 + qt * 64 + wq * 16 + quad * 4 + rr) * 1024 + hh * 64;
        #pragma unroll
        for (int jd = 0; jd < 4; jd++)
            o[base + jd * 16 + r16] = (bf16)(oacc[jd][rr] * inv);
    }
}

// ---------------------------------------------------------------- swiglu: g = silu(x1)*x2, K-padded to 2752 w/ zeros
__global__ void swiglu_kernel(const bf16* __restrict__ x12, bf16* __restrict__ g)
{
    const int kk = blockIdx.x * 256 + threadIdx.x;
    const int row = blockIdx.y;
    if (kk >= FFNP) return;
    float gv = 0.f;
    if (kk < FFN_) {
        const float a  = (float)x12[(size_t)row * X12N + kk];
        const float b2 = (float)x12[(size_t)row * X12N + FFN_ + kk];
        gv = a * b2 / (1.f + __expf(-a));
    }
    g[(size_t)row * FFNP + kk] = (bf16)gv;
}

// ---------------------------------------------------------------- final linear (K=1024 -> 32) + unpatchify
__global__ __launch_bounds__(256) void final_head(
    const bf16* __restrict__ hn, const float* __restrict__ fw, const float* __restrict__ fb,
    float* __restrict__ out)
{
    __shared__ float hs[1024];
    const int row = blockIdx.x, t = threadIdx.x;
    #pragma unroll
    for (int r = 0; r < 4; r++) hs[t + r * 256] = (float)hn[(size_t)row * 1024 + t + r * 256];
    __syncthreads();
    const int o = t >> 3, s = t & 7;
    float acc = 0.f;
    const float* wr = fw + (size_t)o * 1024 + s * 128;
    const float* hb = hs + s * 128;
    for (int e = 0; e < 128; e++) acc += hb[e] * wr[e];
    #pragma unroll
    for (int off = 1; off < 8; off <<= 1) acc += __shfl_xor(acc, off, 64);
    if (s == 0) {
        acc += fb[o];
        const int b = row >> 10, n = row & 1023;
        const int hp = n >> 4, wp = n & 15;
        const int ph = o >> 3, pw = (o >> 1) & 3, c = o & 1;
        out[((size_t)(b * 2 + c) * 256 + hp * 4 + ph) * 64 + wp * 4 + pw] = acc;
    }
}

// ================================================================ launch
extern "C" void kernel_launch(void* const* d_in, const int* in_sizes, int n_in,
                              void* d_out, int out_size, void* d_ws, size_t ws_size,
                              hipStream_t stream)
{
    const float* x       = (const float*)d_in[0];
    const float* t_in    = (const float*)d_in[1];
    const float* patch_w = (const float*)d_in[2];
    const float* patch_b = (const float*)d_in[3];
    const float* t_w     = (const float*)d_in[4];
    const float* t_b     = (const float*)d_in[5];
    const float* norm1_w = (const float*)d_in[6];
    const float* qkv_w   = (const float*)d_in[7];
    const float* qkv_b   = (const float*)d_in[8];
    const float* qn_w    = (const float*)d_in[9];
    const float* kn_w    = (const float*)d_in[10];
    const float* proj_w  = (const float*)d_in[11];
    const float* proj_b  = (const float*)d_in[12];
    const float* norm2_w = (const float*)d_in[13];
    const float* w12_w   = (const float*)d_in[14];
    const float* w12_b   = (const float*)d_in[15];
    const float* w3_w    = (const float*)d_in[16];
    const float* w3_b    = (const float*)d_in[17];
    const float* ada_w   = (const float*)d_in[18];
    const float* ada_b   = (const float*)d_in[19];
    const float* fnorm_w = (const float*)d_in[20];
    const float* flin_w  = (const float*)d_in[21];
    const float* flin_b  = (const float*)d_in[22];
    const float* fada_w  = (const float*)d_in[23];
    const float* fada_b  = (const float*)d_in[24];

    char* ws = (char*)d_ws;
    size_t off = 0;
    auto alloc = [&](size_t nbytes) { char* p = ws + off; off += (nbytes + 255) & ~(size_t)255; return p; };
    float* h     = (float*)alloc((size_t)TOKS * 1024 * 4);    // residual stream fp32
    float* cs    = (float*)alloc(8 * 1024 * 4);               // silu(t-emb)
    float* ada   = (float*)alloc(8 * 6144 * 4);
    float* fada  = (float*)alloc(8 * 2048 * 4);
    bf16*  hn    = (bf16*)alloc((size_t)TOKS * 1024 * 2);
    char*  U1    =         alloc((size_t)TOKS * X12N * 2);    // q,k,v,o during attn; x12 during FFN
    bf16*  qb    = (bf16*)U1;
    bf16*  kb    = qb + (size_t)TOKS * 1024;
    bf16*  vb    = kb + (size_t)TOKS * 1024;   // [bh][d][n] (pre-transposed)
    bf16*  ob    = vb + (size_t)TOKS * 1024;
    bf16*  x12   = (bf16*)U1;
    bf16*  g     = (bf16*)alloc((size_t)TOKS * FFNP * 2);
    bf16*  wqkvb = (bf16*)alloc((size_t)3072 * 1024 * 2);
    bf16*  wprjb = (bf16*)alloc((size_t)1024 * 1024 * 2);
    bf16*  w12b  = (bf16*)alloc((size_t)X12N * 1024 * 2);
    bf16*  w3p   = (bf16*)alloc((size_t)1024 * FFNP * 2);
    (void)ws_size; (void)in_sizes; (void)n_in; (void)out_size;

    small_gemm<<<dim3(1024 / 4), 256, 0, stream>>>(nullptr, t_in, t_w, t_b, cs, 1024, 256, 1, 1);
    patch_embed<<<dim3(TOKS), 256, 0, stream>>>(x, patch_w, patch_b, h);

    for (int d = 0; d < 8; d++) {
        small_gemm<<<dim3(6144 / 4), 256, 0, stream>>>(cs, nullptr,
            ada_w + (size_t)d * 6144 * 1024, ada_b + (size_t)d * 6144, ada, 6144, 1024, 0, 0);
        norm_mod<<<dim3(TOKS), 256, 0, stream>>>(h, norm1_w + (size_t)d * 1024, ada, 0, 1024, 6144, hn);
        conv_bf16<<<dim3(3072 * 1024 / 4 / 256), 256, 0, stream>>>(qkv_w + (size_t)d * 3072 * 1024, wqkvb, 3072 * 1024);
        gemm_bt<<<dim3(3072 / 128, 64), 256, 0, stream>>>(hn,
            wqkvb, qkv_b + (size_t)d * 3072, 1024, 3072, EPI_QKV,
            nullptr, 0, qb, kb, vb, nullptr, nullptr, 0);
        rope_qk<<<dim3(1024, 128), 64, 0, stream>>>(qb, kb, qn_w + (size_t)d * 64, kn_w + (size_t)d * 64);
        attn_kernel<<<dim3(16, 128), 256, 0, stream>>>(qb, kb, vb, ob);
        conv_bf16<<<dim3(1024 * 1024 / 4 / 256), 256, 0, stream>>>(proj_w + (size_t)d * 1024 * 1024, wprjb, 1024 * 1024);
        gemm_bt<<<dim3(1024 / 128, 64), 256, 0, stream>>>(ob,
            wprjb, proj_b + (size_t)d * 1024, 1024, 1024, EPI_RESID,
            nullptr, 0, nullptr, nullptr, nullptr, h, ada + 2048, 6144);
        norm_mod<<<dim3(TOKS), 256, 0, stream>>>(h, norm2_w + (size_t)d * 1024, ada, 3072, 4096, 6144, hn);
        conv_bf16<<<dim3(X12N * 1024 / 4 / 256), 256, 0, stream>>>(w12_w + (size_t)d * X12N * 1024, w12b, X12N * 1024);
        gemm_bt<<<dim3(43, 64), 256, 0, stream>>>(hn,
            w12b, w12_b + (size_t)d * X12N, 1024, X12N, EPI_BF16,
            x12, X12N, nullptr, nullptr, nullptr, nullptr, nullptr, 0);
        swiglu_kernel<<<dim3(11, TOKS), 256, 0, stream>>>(x12, g);
        conv_pad_w3<<<dim3(11, 1024), 256, 0, stream>>>(w3_w + (size_t)d * 1024 * FFN_, w3p);
        gemm_bt<<<dim3(1024 / 128, 64), 256, 0, stream>>>(g,
            w3p, w3_b + (size_t)d * 1024, FFNP, 1024, EPI_RESID,
            nullptr, 0, nullptr, nullptr, nullptr, h, ada + 5120, 6144);
    }

    small_gemm<<<dim3(2048 / 4), 256, 0, stream>>>(cs, nullptr, fada_w, fada_b, fada, 2048, 1024, 0, 0);
    norm_mod<<<dim3(TOKS), 256, 0, stream>>>(h, fnorm_w, fada, 0, 1024, 2048, hn);
    final_head<<<dim3(TOKS), 256, 0, stream>>>(hn, flin_w, flin_b, (float*)d_out);
}